// Round 1
// baseline (7277.490 us; speedup 1.0000x reference)
//
#include <hip/hip_runtime.h>

#define Tn 4096
#define DHn 64
#define NFn 256
#define BHn 64
#define CLD 65            // ws ctx leading dim: 64 v-cols + 1 s col
#define A_CHUNKS 8        // kernel A: T split
#define B_CHUNKS 8        // kernel B: T split
#define A_ROWS (Tn / A_CHUNKS)   // 512
#define B_ROWS (Tn / B_CHUNKS)   // 512
#define BG 16             // kernel B rows per group

static __device__ __forceinline__ float wave_sum(float x) {
#pragma unroll
    for (int off = 32; off > 0; off >>= 1) x += __shfl_xor(x, off);
    return x;
}
static __device__ __forceinline__ float wave_max(float x) {
#pragma unroll
    for (int off = 32; off > 0; off >>= 1) x = fmaxf(x, __shfl_xor(x, off));
    return x;
}

static constexpr float DATA_SCALE = 0.35355339059327379f;  // 64^-0.25
static constexpr float DN_SCALE   = 0.0625f;               // 0.5 * DATA_SCALE^2

// ---------------- Kernel A: ctx[bh][256][65] = sum_t kp_rel[t,d] * [v[t,e], 1] ----
__global__ __launch_bounds__(256, 2)
void perf_ctx_kernel(const float* __restrict__ kk, const float* __restrict__ vv,
                     const float* __restrict__ proj, float* __restrict__ ctxg)
{
    const int bh   = blockIdx.y;
    const int t0   = blockIdx.x * A_ROWS;
    const int tid  = threadIdx.x;          // = feature d (0..255)
    const int lane = tid & 63;
    const int wv   = tid >> 6;

    __shared__ __align__(16) float kbuf[4][DHn];
    __shared__ __align__(16) float vbuf[4][DHn];
    __shared__ float dnbuf[4];
    __shared__ float redmax[4][4];         // [wave][row]

    // proj row `tid` into registers (one-time, L2-cached across blocks)
    float pr[DHn];
#pragma unroll
    for (int j = 0; j < DHn; j += 4) {
        const float4 p4 = *(const float4*)(proj + (size_t)tid * DHn + j);
        pr[j] = p4.x; pr[j + 1] = p4.y; pr[j + 2] = p4.z; pr[j + 3] = p4.w;
    }

    float acc[DHn];
#pragma unroll
    for (int e = 0; e < DHn; e++) acc[e] = 0.f;
    float accs = 0.f;

    const float* kb = kk + (size_t)bh * Tn * DHn;
    const float* vb = vv + (size_t)bh * Tn * DHn;

    const int r = tid >> 6;     // staging: wave r loads row r
    const int e = tid & 63;

    for (int g = 0; g < A_ROWS; g += 4) {
        const int t = t0 + g + r;
        const float kvv = kb[(size_t)t * DHn + e];
        vbuf[r][e] = vb[(size_t)t * DHn + e];
        kbuf[r][e] = kvv;
        const float sq = wave_sum(kvv * kvv);
        if (lane == 0) dnbuf[r] = sq * DN_SCALE;
        __syncthreads();

        // dp for 4 rows: thread d computes dot(proj_d, k_row)
        float dp[4];
#pragma unroll
        for (int rr = 0; rr < 4; rr++) {
            const float4* k4 = (const float4*)&kbuf[rr][0];
            float s0 = 0.f, s1 = 0.f, s2 = 0.f, s3 = 0.f;
#pragma unroll
            for (int j = 0; j < DHn / 4; j++) {
                const float4 kq = k4[j];
                s0 = fmaf(pr[4 * j + 0], kq.x, s0);
                s1 = fmaf(pr[4 * j + 1], kq.y, s1);
                s2 = fmaf(pr[4 * j + 2], kq.z, s2);
                s3 = fmaf(pr[4 * j + 3], kq.w, s3);
            }
            dp[rr] = ((s0 + s1) + (s2 + s3)) * DATA_SCALE;
        }
        // per-row max over all 256 threads (NF axis)
#pragma unroll
        for (int rr = 0; rr < 4; rr++) {
            const float m = wave_max(dp[rr]);
            if (lane == 0) redmax[wv][rr] = m;
        }
        __syncthreads();
#pragma unroll
        for (int rr = 0; rr < 4; rr++) {
            const float m = fmaxf(fmaxf(redmax[0][rr], redmax[1][rr]),
                                  fmaxf(redmax[2][rr], redmax[3][rr]));
            const float w = __expf(dp[rr] - dnbuf[rr] - m);   // kp_rel (scale/EPS cancel)
            accs += w;
            const float4* v4 = (const float4*)&vbuf[rr][0];
#pragma unroll
            for (int j = 0; j < DHn / 4; j++) {
                const float4 vq = v4[j];
                acc[4 * j + 0] = fmaf(w, vq.x, acc[4 * j + 0]);
                acc[4 * j + 1] = fmaf(w, vq.y, acc[4 * j + 1]);
                acc[4 * j + 2] = fmaf(w, vq.z, acc[4 * j + 2]);
                acc[4 * j + 3] = fmaf(w, vq.w, acc[4 * j + 3]);
            }
        }
        __syncthreads();
    }

    float* cb = ctxg + (size_t)bh * NFn * CLD + (size_t)tid * CLD;
#pragma unroll
    for (int e2 = 0; e2 < DHn; e2++) atomicAdd(cb + e2, acc[e2]);
    atomicAdd(cb + DHn, accs);
}

// ---------------- Kernel B: out[t,e] = (qp_rel @ ctx) / (qp_rel @ s) ----------------
__global__ __launch_bounds__(256)
void perf_out_kernel(const float* __restrict__ qq, const float* __restrict__ proj,
                     const float* __restrict__ ctxg, float* __restrict__ out)
{
    const int bh   = blockIdx.y;
    const int t0   = blockIdx.x * B_ROWS;
    const int tid  = threadIdx.x;          // step1: = feature d
    const int lane = tid & 63;
    const int wv   = tid >> 6;

    __shared__ __align__(16) float ctxLDS[NFn][68];      // 68: 16B-aligned rows, pads banks
    __shared__ __align__(16) float wLDS[BG][NFn + 1];    // +1 breaks 4-way bank conflict
    __shared__ __align__(16) float qbuf[BG][DHn];
    __shared__ float redmax[4][BG];
    __shared__ float redden[4][BG];

    // stage ctx (coalesced global read, scatter into padded LDS)
    const float* cb = ctxg + (size_t)bh * NFn * CLD;
    for (int idx = tid; idx < NFn * CLD; idx += 256)
        ctxLDS[idx / CLD][idx % CLD] = cb[idx];

    float pr[DHn];
#pragma unroll
    for (int j = 0; j < DHn; j += 4) {
        const float4 p4 = *(const float4*)(proj + (size_t)tid * DHn + j);
        pr[j] = p4.x; pr[j + 1] = p4.y; pr[j + 2] = p4.z; pr[j + 3] = p4.w;
    }
    __syncthreads();
    const float sReg = ctxLDS[tid][DHn];   // s[d]

    const float* qb = qq + (size_t)bh * Tn * DHn;
    float* ob = out + (size_t)bh * Tn * DHn;

    const int r2 = tid >> 4;      // step2 mapping: row in group
    const int eg = tid & 15;      // step2: 4-col group

    for (int g = 0; g < B_ROWS; g += BG) {
        // stage BG=16 q rows
        *(float4*)&qbuf[r2][eg * 4] =
            *(const float4*)&qb[(size_t)(t0 + g + r2) * DHn + eg * 4];
        __syncthreads();

        // step 1: thread d computes dp for 16 rows, row-max, w, den-partials
        float dp[BG];
#pragma unroll
        for (int rr = 0; rr < BG; rr++) {
            const float4* q4 = (const float4*)&qbuf[rr][0];
            float s0 = 0.f, s1 = 0.f, s2 = 0.f, s3 = 0.f;
#pragma unroll
            for (int j = 0; j < DHn / 4; j++) {
                const float4 qv = q4[j];
                s0 = fmaf(pr[4 * j + 0], qv.x, s0);
                s1 = fmaf(pr[4 * j + 1], qv.y, s1);
                s2 = fmaf(pr[4 * j + 2], qv.z, s2);
                s3 = fmaf(pr[4 * j + 3], qv.w, s3);
            }
            dp[rr] = ((s0 + s1) + (s2 + s3)) * DATA_SCALE;
        }
#pragma unroll
        for (int rr = 0; rr < BG; rr++) {
            const float m = wave_max(dp[rr]);
            if (lane == 0) redmax[wv][rr] = m;
        }
        __syncthreads();
#pragma unroll
        for (int rr = 0; rr < BG; rr++) {
            const float m = fmaxf(fmaxf(redmax[0][rr], redmax[1][rr]),
                                  fmaxf(redmax[2][rr], redmax[3][rr]));
            const float w = __expf(dp[rr] - m);   // per-row scaling cancels in out
            wLDS[rr][tid] = w;
            const float ds = wave_sum(w * sReg);
            if (lane == 0) redden[wv][rr] = ds;
        }
        __syncthreads();

        // step 2: thread (r2, eg) accumulates 4 output cols over d
        {
            const float den = redden[0][r2] + redden[1][r2] +
                              redden[2][r2] + redden[3][r2];
            const float dinv = 1.0f / den;
            float a0 = 0.f, a1 = 0.f, a2 = 0.f, a3 = 0.f;
#pragma unroll 8
            for (int d = 0; d < NFn; d++) {
                const float w = wLDS[r2][d];
                const float4 c4 = *(const float4*)&ctxLDS[d][eg * 4];
                a0 = fmaf(w, c4.x, a0);
                a1 = fmaf(w, c4.y, a1);
                a2 = fmaf(w, c4.z, a2);
                a3 = fmaf(w, c4.w, a3);
            }
            float4 o;
            o.x = a0 * dinv; o.y = a1 * dinv; o.z = a2 * dinv; o.w = a3 * dinv;
            *(float4*)&ob[(size_t)(t0 + g + r2) * DHn + eg * 4] = o;
        }
        __syncthreads();
    }
}

extern "C" void kernel_launch(void* const* d_in, const int* in_sizes, int n_in,
                              void* d_out, int out_size, void* d_ws, size_t ws_size,
                              hipStream_t stream) {
    const float* q    = (const float*)d_in[0];
    const float* k    = (const float*)d_in[1];
    const float* v    = (const float*)d_in[2];
    const float* proj = (const float*)d_in[3];
    float* out = (float*)d_out;
    float* ctx = (float*)d_ws;

    (void)in_sizes; (void)n_in; (void)out_size; (void)ws_size;

    hipMemsetAsync(ctx, 0, (size_t)BHn * NFn * CLD * sizeof(float), stream);
    perf_ctx_kernel<<<dim3(A_CHUNKS, BHn), 256, 0, stream>>>(k, v, proj, ctx);
    perf_out_kernel<<<dim3(B_CHUNKS, BHn), 256, 0, stream>>>(q, proj, ctx, out);
}

// Round 2
// 395.263 us; speedup vs baseline: 18.4118x; 18.4118x over previous
//
#include <hip/hip_runtime.h>

typedef _Float16 f16;
typedef __attribute__((ext_vector_type(4))) _Float16 f16x4;
typedef __attribute__((ext_vector_type(8))) _Float16 f16x8;
typedef __attribute__((ext_vector_type(4))) float f32x4;

#define Tn 4096
#define DHn 64
#define NFn 256
#define BHn 64
#define TCH 64                 // t-rows per chunk
#define NCH 8                  // chunks per block
#define TBLK (TCH * NCH)       // 512 rows per block
#define GRIDX (Tn / TBLK)      // 8
#define KLD 72                 // kLDS/qLDS/vT leading dim (f16), 16B-aligned rows
#define WLDA 72                // kernel A wLDS [nf][t] stride
#define WLDB 264               // kernel B wLDS/ctxLDS [.][nf] stride (256+8)

static constexpr float DS  = 0.35355339059327379f;  // 64^-0.25 (folded into proj)
static constexpr float DNS = 0.0625f;               // 0.5 * DS^2

// ============ Kernel A: ctx[bh][dh][nf] (+ s row) = sum_t kp[t,nf]*[v,1] ============
__global__ __launch_bounds__(256, 2)
void perf_ctx_mfma(const float* __restrict__ K, const float* __restrict__ V,
                   const float* __restrict__ P, float* __restrict__ ctxws)
{
    __shared__ __align__(16) f16 kLDS[TCH * KLD];
    __shared__ __align__(16) f16 vT[DHn * KLD];     // [dh][t], 8-block XOR swizzled
    __shared__ __align__(16) f16 wLDS[NFn * WLDA];  // [nf][t]
    __shared__ float dn[TCH];
    __shared__ __align__(16) float redmax[TCH][4];

    const int bh   = blockIdx.y;
    const int tid  = threadIdx.x;
    const int lane = tid & 63;
    const int wv   = tid >> 6;
    const int c    = lane & 15;
    const int g    = lane >> 4;

    // proj B-frags in regs (DS folded): nf = 64*wv+16*nt+c, dh = 32*kc+8*g+j
    f16x8 pb[4][2];
#pragma unroll
    for (int nt = 0; nt < 4; nt++)
#pragma unroll
        for (int kc = 0; kc < 2; kc++) {
            const float* s = P + (size_t)(64 * wv + 16 * nt + c) * DHn + 32 * kc + 8 * g;
            f16x8 h;
#pragma unroll
            for (int j = 0; j < 8; j++) h[j] = (f16)(s[j] * DS);
            pb[nt][kc] = h;
        }

    f32x4 cacc[4][4];
#pragma unroll
    for (int a = 0; a < 4; a++)
#pragma unroll
        for (int b = 0; b < 4; b++) cacc[a][b] = (f32x4){0.f, 0.f, 0.f, 0.f};
    float sp[4] = {0.f, 0.f, 0.f, 0.f};

    const float* Kb = K + (size_t)bh * Tn * DHn;
    const float* Vb = V + (size_t)bh * Tn * DHn;
    const int rb = 4 * wv + g;   // tid>>4

    for (int ch = 0; ch < NCH; ch++) {
        const int t0 = blockIdx.x * TBLK + ch * TCH;
        float4 kq[4], vq[4];
#pragma unroll
        for (int i = 0; i < 4; i++) {
            const int r = 16 * i + rb;
            kq[i] = *(const float4*)(Kb + (size_t)(t0 + r) * DHn + 4 * c);
            vq[i] = *(const float4*)(Vb + (size_t)(t0 + r) * DHn + 4 * c);
        }
#pragma unroll
        for (int i = 0; i < 4; i++) {
            const int r = 16 * i + rb;
            f16x4 hk;
            hk[0] = (f16)kq[i].x; hk[1] = (f16)kq[i].y;
            hk[2] = (f16)kq[i].z; hk[3] = (f16)kq[i].w;
            *(f16x4*)&kLDS[r * KLD + 4 * c] = hk;
            float p = kq[i].x * kq[i].x + kq[i].y * kq[i].y +
                      kq[i].z * kq[i].z + kq[i].w * kq[i].w;
            p += __shfl_xor(p, 1); p += __shfl_xor(p, 2);
            p += __shfl_xor(p, 4); p += __shfl_xor(p, 8);
            if (c == 0) dn[r] = p * DNS;
            const float* vf = &vq[i].x;
#pragma unroll
            for (int m = 0; m < 4; m++) {
                const int dh = 4 * c + m;
                vT[dh * KLD + ((((r >> 3) ^ ((dh >> 3) & 7)) << 3) | (r & 7))] = (f16)vf[m];
            }
        }
        __syncthreads();   // S1: staging done

        // GEMM1: dp[t][nf] = K f16 . (DS*proj)^T
        f32x4 dp[4][4];
#pragma unroll
        for (int a = 0; a < 4; a++)
#pragma unroll
            for (int b = 0; b < 4; b++) dp[a][b] = (f32x4){0.f, 0.f, 0.f, 0.f};
#pragma unroll
        for (int mt = 0; mt < 4; mt++) {
            const f16x8 a0 = *(const f16x8*)&kLDS[(16 * mt + c) * KLD + 8 * g];
            const f16x8 a1 = *(const f16x8*)&kLDS[(16 * mt + c) * KLD + 32 + 8 * g];
#pragma unroll
            for (int nt = 0; nt < 4; nt++) {
                dp[mt][nt] = __builtin_amdgcn_mfma_f32_16x16x32_f16(a0, pb[nt][0], dp[mt][nt], 0, 0, 0);
                dp[mt][nt] = __builtin_amdgcn_mfma_f32_16x16x32_f16(a1, pb[nt][1], dp[mt][nt], 0, 0, 0);
            }
        }
        // per-row (t) max over this wave's 64 nf, then cross-wave via LDS
#pragma unroll
        for (int mt = 0; mt < 4; mt++)
#pragma unroll
            for (int r = 0; r < 4; r++) {
                float m = fmaxf(fmaxf(dp[mt][0][r], dp[mt][1][r]),
                                fmaxf(dp[mt][2][r], dp[mt][3][r]));
                m = fmaxf(m, __shfl_xor(m, 1)); m = fmaxf(m, __shfl_xor(m, 2));
                m = fmaxf(m, __shfl_xor(m, 4)); m = fmaxf(m, __shfl_xor(m, 8));
                if (c == 0) redmax[16 * mt + 4 * g + r][wv] = m;
            }
        __syncthreads();   // S2: redmax ready

#pragma unroll
        for (int mt = 0; mt < 4; mt++) {
            float mx[4];
#pragma unroll
            for (int r = 0; r < 4; r++) {
                const int t = 16 * mt + 4 * g + r;
                const f32x4 rm = *(const f32x4*)&redmax[t][0];
                mx[r] = fmaxf(fmaxf(rm[0], rm[1]), fmaxf(rm[2], rm[3])) + dn[t];
            }
#pragma unroll
            for (int nt = 0; nt < 4; nt++) {
                f16x4 hw;
#pragma unroll
                for (int r = 0; r < 4; r++) {
                    const float w = __expf(dp[mt][nt][r] - mx[r]);  // kp (scale/EPS cancel)
                    sp[nt] += w;
                    hw[r] = (f16)w;
                }
                *(f16x4*)&wLDS[(64 * wv + 16 * nt + c) * WLDA + 16 * mt + 4 * g] = hw;
            }
        }
        __syncthreads();   // S3: wLDS ready

        // GEMM2: ctx[nf][dh] += w^T(t->) . V
#pragma unroll
        for (int kc = 0; kc < 2; kc++) {
            f16x8 af[4], bf[4];
#pragma unroll
            for (int mt2 = 0; mt2 < 4; mt2++)
                af[mt2] = *(const f16x8*)&wLDS[(64 * wv + 16 * mt2 + c) * WLDA + 32 * kc + 8 * g];
#pragma unroll
            for (int nt2 = 0; nt2 < 4; nt2++) {
                const int dh = 16 * nt2 + c;
                const int tb = 4 * kc + g;
                bf[nt2] = *(const f16x8*)&vT[dh * KLD + ((tb ^ ((dh >> 3) & 7)) << 3)];
            }
#pragma unroll
            for (int mt2 = 0; mt2 < 4; mt2++)
#pragma unroll
                for (int nt2 = 0; nt2 < 4; nt2++)
                    cacc[mt2][nt2] = __builtin_amdgcn_mfma_f32_16x16x32_f16(
                        af[mt2], bf[nt2], cacc[mt2][nt2], 0, 0, 0);
        }
        __syncthreads();   // Send: protect kLDS/vT for next chunk
    }

    float* cb = ctxws + (size_t)bh * 65 * NFn;
#pragma unroll
    for (int mt2 = 0; mt2 < 4; mt2++)
#pragma unroll
        for (int nt2 = 0; nt2 < 4; nt2++)
#pragma unroll
            for (int r = 0; r < 4; r++)
                atomicAdd(&cb[(size_t)(16 * nt2 + c) * NFn + 64 * wv + 16 * mt2 + 4 * g + r],
                          cacc[mt2][nt2][r]);
#pragma unroll
    for (int nt = 0; nt < 4; nt++) {
        float sv = sp[nt];
        sv += __shfl_xor(sv, 16); sv += __shfl_xor(sv, 32);
        if (g == 0) atomicAdd(&cb[64 * NFn + 64 * wv + 16 * nt + c], sv);
    }
}

// ============ Kernel B: out[t][dh] = (qp . ctx) / (qp . s) ============
__global__ __launch_bounds__(256, 2)
void perf_out_mfma(const float* __restrict__ Q, const float* __restrict__ P,
                   const float* __restrict__ ctxws, float* __restrict__ Out)
{
    __shared__ __align__(16) f16 qLDS[TCH * KLD];
    __shared__ __align__(16) f16 wLDS[TCH * WLDB];    // [t][nf]
    __shared__ __align__(16) f16 ctxLDS[DHn * WLDB];  // [dh][nf]
    __shared__ float sLDS[NFn];
    __shared__ __align__(16) float redmax[TCH][4];
    __shared__ __align__(16) float denP[TCH][4];

    const int bh   = blockIdx.y;
    const int tid  = threadIdx.x;
    const int lane = tid & 63;
    const int wv   = tid >> 6;
    const int c    = lane & 15;
    const int g    = lane >> 4;

    f16x8 pb[4][2];
#pragma unroll
    for (int nt = 0; nt < 4; nt++)
#pragma unroll
        for (int kc = 0; kc < 2; kc++) {
            const float* s = P + (size_t)(64 * wv + 16 * nt + c) * DHn + 32 * kc + 8 * g;
            f16x8 h;
#pragma unroll
            for (int j = 0; j < 8; j++) h[j] = (f16)(s[j] * DS);
            pb[nt][kc] = h;
        }

    // stage ctx (f32 -> f16) and s
    const float* cb = ctxws + (size_t)bh * 65 * NFn;
    {
        const int dh = tid >> 2;
        const int nq = (tid & 3) * 64;
#pragma unroll
        for (int u = 0; u < 16; u++) {
            const float4 cv = *(const float4*)&cb[(size_t)dh * NFn + nq + 4 * u];
            f16x4 h;
            h[0] = (f16)cv.x; h[1] = (f16)cv.y; h[2] = (f16)cv.z; h[3] = (f16)cv.w;
            *(f16x4*)&ctxLDS[dh * WLDB + nq + 4 * u] = h;
        }
        sLDS[tid] = cb[64 * NFn + tid];
    }
    __syncthreads();
    float s4[4];
#pragma unroll
    for (int nt = 0; nt < 4; nt++) s4[nt] = sLDS[64 * wv + 16 * nt + c];

    const float* Qb = Q + (size_t)bh * Tn * DHn;
    float* Ob = Out + (size_t)bh * Tn * DHn;
    const int rb = 4 * wv + g;

    for (int ch = 0; ch < NCH; ch++) {
        const int t0 = blockIdx.x * TBLK + ch * TCH;
#pragma unroll
        for (int i = 0; i < 4; i++) {
            const int r = 16 * i + rb;
            const float4 qv = *(const float4*)(Qb + (size_t)(t0 + r) * DHn + 4 * c);
            f16x4 h;
            h[0] = (f16)qv.x; h[1] = (f16)qv.y; h[2] = (f16)qv.z; h[3] = (f16)qv.w;
            *(f16x4*)&qLDS[r * KLD + 4 * c] = h;
        }
        __syncthreads();   // S1

        f32x4 dp[4][4];
#pragma unroll
        for (int a = 0; a < 4; a++)
#pragma unroll
            for (int b = 0; b < 4; b++) dp[a][b] = (f32x4){0.f, 0.f, 0.f, 0.f};
#pragma unroll
        for (int mt = 0; mt < 4; mt++) {
            const f16x8 a0 = *(const f16x8*)&qLDS[(16 * mt + c) * KLD + 8 * g];
            const f16x8 a1 = *(const f16x8*)&qLDS[(16 * mt + c) * KLD + 32 + 8 * g];
#pragma unroll
            for (int nt = 0; nt < 4; nt++) {
                dp[mt][nt] = __builtin_amdgcn_mfma_f32_16x16x32_f16(a0, pb[nt][0], dp[mt][nt], 0, 0, 0);
                dp[mt][nt] = __builtin_amdgcn_mfma_f32_16x16x32_f16(a1, pb[nt][1], dp[mt][nt], 0, 0, 0);
            }
        }
#pragma unroll
        for (int mt = 0; mt < 4; mt++)
#pragma unroll
            for (int r = 0; r < 4; r++) {
                float m = fmaxf(fmaxf(dp[mt][0][r], dp[mt][1][r]),
                                fmaxf(dp[mt][2][r], dp[mt][3][r]));
                m = fmaxf(m, __shfl_xor(m, 1)); m = fmaxf(m, __shfl_xor(m, 2));
                m = fmaxf(m, __shfl_xor(m, 4)); m = fmaxf(m, __shfl_xor(m, 8));
                if (c == 0) redmax[16 * mt + 4 * g + r][wv] = m;
            }
        __syncthreads();   // S2

#pragma unroll
        for (int mt = 0; mt < 4; mt++) {
            float mx[4], dsum[4];
#pragma unroll
            for (int r = 0; r < 4; r++) {
                const int t = 16 * mt + 4 * g + r;
                const f32x4 rm = *(const f32x4*)&redmax[t][0];
                mx[r] = fmaxf(fmaxf(rm[0], rm[1]), fmaxf(rm[2], rm[3]));
                dsum[r] = 0.f;
            }
#pragma unroll
            for (int nt = 0; nt < 4; nt++)
#pragma unroll
                for (int r = 0; r < 4; r++) {
                    const float w = __expf(dp[mt][nt][r] - mx[r]);  // q-side row factors cancel
                    wLDS[(16 * mt + 4 * g + r) * WLDB + 64 * wv + 16 * nt + c] = (f16)w;
                    dsum[r] += w * s4[nt];
                }
#pragma unroll
            for (int r = 0; r < 4; r++) {
                float d = dsum[r];
                d += __shfl_xor(d, 1); d += __shfl_xor(d, 2);
                d += __shfl_xor(d, 4); d += __shfl_xor(d, 8);
                if (c == 0) denP[16 * mt + 4 * g + r][wv] = d;
            }
        }
        __syncthreads();   // S3

        // GEMM2: out-tile = w . ctx  (wave wv owns t rows [16wv,16wv+16))
        f32x4 oacc[4];
#pragma unroll
        for (int nt2 = 0; nt2 < 4; nt2++) oacc[nt2] = (f32x4){0.f, 0.f, 0.f, 0.f};
#pragma unroll
        for (int kc = 0; kc < 8; kc++) {
            const f16x8 a = *(const f16x8*)&wLDS[(16 * wv + c) * WLDB + 32 * kc + 8 * g];
#pragma unroll
            for (int nt2 = 0; nt2 < 4; nt2++) {
                const f16x8 b = *(const f16x8*)&ctxLDS[(16 * nt2 + c) * WLDB + 32 * kc + 8 * g];
                oacc[nt2] = __builtin_amdgcn_mfma_f32_16x16x32_f16(a, b, oacc[nt2], 0, 0, 0);
            }
        }
#pragma unroll
        for (int r = 0; r < 4; r++) {
            const int t = 16 * wv + 4 * g + r;
            const f32x4 d4 = *(const f32x4*)&denP[t][0];
            const float dinv = __builtin_amdgcn_rcpf(d4[0] + d4[1] + d4[2] + d4[3]);
#pragma unroll
            for (int nt2 = 0; nt2 < 4; nt2++)
                Ob[(size_t)(t0 + t) * DHn + 16 * nt2 + c] = oacc[nt2][r] * dinv;
        }
        __syncthreads();   // Send
    }
}

extern "C" void kernel_launch(void* const* d_in, const int* in_sizes, int n_in,
                              void* d_out, int out_size, void* d_ws, size_t ws_size,
                              hipStream_t stream) {
    const float* q    = (const float*)d_in[0];
    const float* k    = (const float*)d_in[1];
    const float* v    = (const float*)d_in[2];
    const float* proj = (const float*)d_in[3];
    float* out = (float*)d_out;
    float* ctx = (float*)d_ws;

    (void)in_sizes; (void)n_in; (void)out_size; (void)ws_size;

    hipMemsetAsync(ctx, 0, (size_t)BHn * 65 * NFn * sizeof(float), stream);
    perf_ctx_mfma<<<dim3(GRIDX, BHn), 256, 0, stream>>>(k, v, proj, ctx);
    perf_out_mfma<<<dim3(GRIDX, BHn), 256, 0, stream>>>(q, proj, ctx, out);
}